// Round 1
// baseline (939.365 us; speedup 1.0000x reference)
//
#include <hip/hip_runtime.h>
#include <math.h>

#define PI_D 3.14159265358979323846264338327950288

// problem constants
#define NPIX 128
#define NFFT 512
#define BATCH 64

__device__ __forceinline__ float2 cmulf(float2 a, float2 b) {
    return make_float2(a.x*b.x - a.y*b.y, a.x*b.y + a.y*b.x);
}

// ---------------------------------------------------------------------------
// Stockham radix-2 512-point FFT, 256 threads, LDS ping-pong.
// twl[a] = exp(-2*pi*i*a/512). isign=+1: forward DFT; isign=-1: unnormalized
// inverse DFT. Data starts in b[cur]; returns buffer index holding the result
// (natural order). Caller must __syncthreads() after loading b[cur].
// ---------------------------------------------------------------------------
__device__ __forceinline__ int fft512f(float2 (*b)[NFFT], const float2* twl,
                                       int t, float isign, int cur)
{
#pragma unroll
    for (int st = 0; st < 9; ++st) {
        const int s = 1 << st;
        const int p = t >> st;
        const int q = t & (s - 1);
        const int m = 256 >> st;
        const float2 a = b[cur][q + s*p];
        const float2 c = b[cur][q + s*(p + m)];
        float2 w = twl[p << st];
        w.y *= isign;
        const float2 dif = make_float2(a.x - c.x, a.y - c.y);
        b[cur^1][q + 2*s*p]     = make_float2(a.x + c.x, a.y + c.y);
        b[cur^1][q + 2*s*p + s] = make_float2(dif.x*w.x - dif.y*w.y,
                                              dif.x*w.y + dif.y*w.x);
        cur ^= 1;
        __syncthreads();
    }
    return cur;
}

// double-precision variant (used only for building H once per launch)
__device__ __forceinline__ int fft512d(double2 (*b)[NFFT], int t, double isign, int cur)
{
    for (int st = 0; st < 9; ++st) {
        const int s = 1 << st;
        const int p = t >> st;
        const int q = t & (s - 1);
        const int m = 256 >> st;
        const double2 a = b[cur][q + s*p];
        const double2 c = b[cur][q + s*(p + m)];
        double sw, cw;
        sincos(isign * (-PI_D/256.0) * (double)(p << st), &sw, &cw);
        const double2 dif = make_double2(a.x - c.x, a.y - c.y);
        b[cur^1][q + 2*s*p]     = make_double2(a.x + c.x, a.y + c.y);
        b[cur^1][q + 2*s*p + s] = make_double2(dif.x*cw - dif.y*sw,
                                               dif.x*sw + dif.y*cw);
        cur ^= 1;
        __syncthreads();
    }
    return cur;
}

// ---------------------------------------------------------------------------
// setup kernels
// ---------------------------------------------------------------------------
__global__ __launch_bounds__(256) void k_twiddle(float2* tw)
{
    int a = threadIdx.x;            // 256 threads
    double s, c;
    sincos(-2.0*PI_D*(double)a/512.0, &s, &c);
    tw[a] = make_float2((float)c, (float)s);
}

// flipped Rayleigh-Sommerfeld kernel, zero-padded into 512x512 (double)
__global__ __launch_bounds__(256) void k_build_w(double2* Wd)
{
    const double WLEN = 5.32e-07, PIX = 1.0e-4, DIST = 0.005;
    int idx = blockIdx.x*blockDim.x + threadIdx.x;   // 512*512 total
    int i = idx >> 9, j = idx & 511;
    double2 v = make_double2(0.0, 0.0);
    if (i < 257 && j < 257) {
        // store w[::-1,::-1]: value at (i,j) is w[256-i][256-j]
        double cx = (double)(128 - i) * PIX;   // c[256-i] = ((256-i)-128)*PIX
        double cy = (double)(128 - j) * PIX;
        double r2 = cx*cx + cy*cy + DIST*DIST;
        double r  = sqrt(r2);
        double sc = PIX*PIX*DIST / r2;
        double re_a = 1.0/(2.0*PI_D*r);
        double im_a = -1.0/WLEN;               // 1/(WL*i) = -i/WL
        double sp, cp;
        sincos(2.0*PI_D*r/WLEN, &sp, &cp);
        v.x = sc*(re_a*cp - im_a*sp);
        v.y = sc*(re_a*sp + im_a*cp);
    }
    Wd[idx] = v;
}

__global__ __launch_bounds__(256) void k_dfft_row(const double2* in, double2* out)
{
    __shared__ double2 b[2][NFFT];
    int row = blockIdx.x, t = threadIdx.x;
    b[0][t]       = in[row*NFFT + t];
    b[0][t + 256] = in[row*NFFT + t + 256];
    __syncthreads();
    int cur = fft512d(b, t, 1.0, 0);
    out[row*NFFT + t]       = b[cur][t];
    out[row*NFFT + t + 256] = b[cur][t + 256];
}

// column FFT; writes H TRANSPOSED (Ht[col*512 + f]) as float2, with the
// whole inverse-normalization 1/512^2 folded in.
__global__ __launch_bounds__(256) void k_dfft_col_H(const double2* in, float2* Ht)
{
    __shared__ double2 b[2][NFFT];
    int col = blockIdx.x, t = threadIdx.x;
    b[0][t]       = in[t*NFFT + col];
    b[0][t + 256] = in[(t + 256)*NFFT + col];
    __syncthreads();
    int cur = fft512d(b, t, 1.0, 0);
    const double scale = 1.0/(512.0*512.0);
    Ht[col*NFFT + t]       = make_float2((float)(b[cur][t].x*scale),
                                         (float)(b[cur][t].y*scale));
    Ht[col*NFFT + t + 256] = make_float2((float)(b[cur][t+256].x*scale),
                                         (float)(b[cur][t+256].y*scale));
}

// initial field: xc0 = x + 0i  -> Fcur and output chunk 1
__global__ __launch_bounds__(256) void k_init(const float* x, float2* Fcur,
                                              float2* outc, float* outr)
{
    int idx = blockIdx.x*blockDim.x + threadIdx.x;   // 1048576 total
    float v = x[idx];
    float2 c = make_float2(v, 0.f);
    Fcur[idx] = c;
    if (outc) outc[idx] = c;
    else      outr[idx] = v;
}

// ---------------------------------------------------------------------------
// propagation passes
// ---------------------------------------------------------------------------
// pass A: per (img,row<128): 128-point row zero-padded -> 512 forward FFT
__global__ __launch_bounds__(256) void k_passA(const float2* Fcur, float2* Abuf,
                                               const float2* twg)
{
    __shared__ float2 b[2][NFFT];
    __shared__ float2 twl[256];
    int row = blockIdx.x, img = blockIdx.y, t = threadIdx.x;
    twl[t] = twg[t];
    float2 z = make_float2(0.f, 0.f);
    b[0][t]       = (t < NPIX) ? Fcur[(img*NPIX + row)*NPIX + t] : z;
    b[0][t + 256] = z;
    __syncthreads();
    int cur = fft512f(b, twl, t, 1.f, 0);
    Abuf[(img*NPIX + row)*NFFT + t]       = b[cur][t];
    Abuf[(img*NPIX + row)*NFFT + t + 256] = b[cur][t + 256];
}

// pass BC (fused): per (img,col): column fwd FFT (128 nonzero) * H * inverse
// column FFT; keep spatial rows 128..255, written in place over Abuf rows 0..127.
__global__ __launch_bounds__(256) void k_passBC(float2* Abuf, const float2* Ht,
                                                const float2* twg)
{
    __shared__ float2 b[2][NFFT];
    __shared__ float2 twl[256];
    __shared__ float2 hcol[NFFT];
    int col = blockIdx.x, img = blockIdx.y, t = threadIdx.x;
    twl[t] = twg[t];
    float2* base = Abuf + (size_t)img*NPIX*NFFT;
    float2 z = make_float2(0.f, 0.f);
    b[0][t]       = (t < NPIX) ? base[t*NFFT + col] : z;
    b[0][t + 256] = z;
    hcol[t]       = Ht[col*NFFT + t];         // coalesced: H stored transposed
    hcol[t + 256] = Ht[col*NFFT + t + 256];
    __syncthreads();
    int cur = fft512f(b, twl, t, 1.f, 0);     // forward along rows-axis
    float2 v0 = cmulf(b[cur][t],       hcol[t]);
    float2 v1 = cmulf(b[cur][t + 256], hcol[t + 256]);
    __syncthreads();
    b[cur][t]       = v0;
    b[cur][t + 256] = v1;
    __syncthreads();
    cur = fft512f(b, twl, t, -1.f, cur);      // inverse (scale folded into H)
    if (t < NPIX) base[t*NFFT + col] = b[cur][t + NPIX];  // keep rows 128..255
}

// pass D: per (img,row'): 512 inverse row FFT, keep cols 128..255, apply phase
// mask (layers 0..4), write next field + output chunk (+ |.|^2 on final step)
__global__ __launch_bounds__(256) void k_passD(const float2* Abuf, const float* phases,
                                               float2* outc, float* outr,
                                               float* outabs, float2* Fnext,
                                               const float2* twg, int layer)
{
    __shared__ float2 b[2][NFFT];
    __shared__ float2 twl[256];
    int row = blockIdx.x, img = blockIdx.y, t = threadIdx.x;
    twl[t] = twg[t];
    b[0][t]       = Abuf[(img*NPIX + row)*NFFT + t];
    b[0][t + 256] = Abuf[(img*NPIX + row)*NFFT + t + 256];
    __syncthreads();
    int cur = fft512f(b, twl, t, -1.f, 0);    // inverse (scale folded into H)
    if (t < NPIX) {
        float2 v = b[cur][t + NPIX];          // crop cols 128..255
        if (layer < 5) {
            float p  = phases[layer*4096 + (row >> 1)*64 + (t >> 1)];
            float cp = 6.2831853071795864769f * (1.f/(1.f + expf(-p)));
            float sn, cs;
            sincosf(cp, &sn, &cs);
            v = cmulf(v, make_float2(cs, sn));
        }
        int o = (img*NPIX + row)*NPIX + t;
        Fnext[o] = v;
        if (outc) outc[o] = v;
        else      outr[o] = v.x;
        if (layer == 5) outabs[o] = v.x*v.x + v.y*v.y;
    }
}

// ---------------------------------------------------------------------------
extern "C" void kernel_launch(void* const* d_in, const int* in_sizes, int n_in,
                              void* d_out, int out_size, void* d_ws, size_t ws_size,
                              hipStream_t stream)
{
    const float* x      = (const float*)d_in[0];   // [64,128,128]
    const float* phases = (const float*)d_in[1];   // [5,64,64]
    float* out = (float*)d_out;
    char*  ws  = (char*)d_ws;

    // workspace layout
    float2* tw   = (float2*)ws;                                   // 2 KB
    float2* Ht   = (float2*)(ws + 4096);                          // 2 MB
    float2* Fcur = (float2*)(ws + 4096 + (size_t)NFFT*NFFT*8);    // 8.4 MB
    float2* Abuf = (float2*)(ws + 4096 + (size_t)NFFT*NFFT*8
                                      + (size_t)BATCH*NPIX*NPIX*8); // 33.6 MB
    // double temporaries for H construction alias the (not-yet-used) Abuf
    double2* Wd = (double2*)Abuf;
    double2* Td = (double2*)((char*)Abuf + (size_t)NFFT*NFFT*16);

    // output layout: chunk0 = x_abs (1048576 f32); chunks 1..7 complex fields.
    // interleaved re/im (2097152 f32 each) if out_size carries them; otherwise
    // real parts only.
    const bool   inter   = (out_size >= 15728640);
    const size_t cstride = inter ? 2097152u : 1048576u;

    k_twiddle   <<<1,    256, 0, stream>>>(tw);
    k_build_w   <<<1024, 256, 0, stream>>>(Wd);
    k_dfft_row  <<<NFFT, 256, 0, stream>>>(Wd, Td);
    k_dfft_col_H<<<NFFT, 256, 0, stream>>>(Td, Ht);

    {
        float* c1 = out + 1048576;
        k_init<<<4096, 256, 0, stream>>>(x, Fcur,
                                         inter ? (float2*)c1 : nullptr,
                                         inter ? nullptr : c1);
    }

    for (int step = 0; step < 6; ++step) {
        k_passA <<<dim3(NPIX, BATCH), 256, 0, stream>>>(Fcur, Abuf, tw);
        k_passBC<<<dim3(NFFT, BATCH), 256, 0, stream>>>(Abuf, Ht, tw);
        float* chunk = out + 1048576 + (size_t)(step + 1)*cstride;
        k_passD <<<dim3(NPIX, BATCH), 256, 0, stream>>>(
            Abuf, phases,
            inter ? (float2*)chunk : nullptr,
            inter ? nullptr : chunk,
            out /* x_abs chunk0 */, Fcur, tw, step);
    }
}